// Round 1
// baseline (235.076 us; speedup 1.0000x reference)
//
#include <hip/hip_runtime.h>
#include <math.h>

// GMM EM, M=4 mixtures x G=4 gaussians, C=3, EM_ITERS=3, EPS=1e-4.
// R7: kill the DS-pipe bottleneck. All quad-broadcast __shfl (8/src-step in
// accum, 16 transpose + 12 broadcast in final) -> DPP quad_perm (VALU, no
// lgkmcnt). Wave reduce xor4/xor8 -> DPP row_ror:4/8. Grid 512->1024 blocks
// (4 blocks/CU, 4 waves/SIMD; VGPR pinned <=128 via launch_bounds(256,4));
// trips==1 at N=2^20. Atomic combine widened to 8 banks (same per-address
// serialization at 2x blocks). Structure otherwise R6: lane role q = lane&3
// owns mixture q, acc[40]/PR[40] in regs, masked FMA accumulate, banked
// global unsafeAtomicAdd, every block re-derives 16x12 params from sums.
// Pipeline: memset(15KB) -> accum0 -> accum1 -> accum2 -> final.

#define NTHR  256
#define NBLK  1024
#define NBANK 8
#define EPS_F 1e-4f
#define LOG2PI3 5.5136311992280366f   // 3*ln(2*pi)

// DPP helpers: ctrl 0x00-0xFF = quad_perm (src*0x55 = quad broadcast of src),
// 0x124 = row_ror:4, 0x128 = row_ror:8 (rows of 16 lanes).
template<int CTRL>
__device__ __forceinline__ float dpp_f(float v) {
    return __int_as_float(
        __builtin_amdgcn_mov_dpp(__float_as_int(v), CTRL, 0xF, 0xF, false));
}
template<int CTRL>
__device__ __forceinline__ int dpp_i(int v) {
    return __builtin_amdgcn_mov_dpp(v, CTRL, 0xF, 0xF, false);
}

// sums buffer per pass: [160 slots][NBANK banks] floats (slot = t*10+k)

// Derive E-step params from banked sums. spar layout per cluster t, stride 12:
// [0..2]=P*mu, [3]=c0, [4..6]=-0.5*Pii, [7..9]=-Pij(01,02,12), [10..11]=pad
static __device__ void compute_params(const float* __restrict__ sumsIn,
                                      float* spar, float* sums, float* wtab,
                                      int tid) {
    if (tid < 160) {
        float4 v0 = ((const float4*)sumsIn)[tid * 2];      // 8 banks
        float4 v1 = ((const float4*)sumsIn)[tid * 2 + 1];
        sums[tid] = ((v0.x + v0.y) + (v0.z + v0.w))
                  + ((v1.x + v1.y) + (v1.z + v1.w));
    }
    __syncthreads();
    if (tid < 16) wtab[tid] = sums[tid * 10] + EPS_F;
    __syncthreads();
    if (tid < 16) {
        const int tt = tid;
        const float* S = &sums[tt * 10];
        const float w  = wtab[tt];
        const float iw = 1.0f / w;
        float mu0 = S[1] * iw, mu1 = S[2] * iw, mu2 = S[3] * iw;
        float c00 = S[4] * iw - mu0 * mu0 + EPS_F;
        float c01 = S[5] * iw - mu0 * mu1;
        float c02 = S[6] * iw - mu0 * mu2;
        float c11 = S[7] * iw - mu1 * mu1 + EPS_F;
        float c12 = S[8] * iw - mu1 * mu2;
        float c22 = S[9] * iw - mu2 * mu2 + EPS_F;
        float d00 = c11 * c22 - c12 * c12;
        float d01 = c02 * c12 - c01 * c22;
        float d02 = c01 * c12 - c02 * c11;
        float det = c00 * d00 + c01 * d01 + c02 * d02;
        float idet = 1.0f / det;
        float P00 = d00 * idet, P01 = d01 * idet, P02 = d02 * idet;
        float P11 = (c00 * c22 - c02 * c02) * idet;
        float P12 = (c01 * c02 - c00 * c12) * idet;
        float P22 = (c00 * c11 - c01 * c01) * idet;
        float logdet = logf(det);
        const int mb = tt & 12;
        float wsum = wtab[mb] + wtab[mb + 1] + wtab[mb + 2] + wtab[mb + 3];
        float logpi = logf(w) - logf(wsum);
        float pm0 = P00 * mu0 + P01 * mu1 + P02 * mu2;
        float pm1 = P01 * mu0 + P11 * mu1 + P12 * mu2;
        float pm2 = P02 * mu0 + P12 * mu1 + P22 * mu2;
        float mPm = mu0 * pm0 + mu1 * pm1 + mu2 * pm2;
        float c0 = logpi - 0.5f * (mPm + logdet + LOG2PI3);
        float* P = spar + tt * 12;
        P[0] = pm0; P[1] = pm1; P[2] = pm2; P[3] = c0;
        P[4] = -0.5f * P00; P[5] = -0.5f * P11; P[6] = -0.5f * P22;
        P[7] = -P01; P[8] = -P02; P[9] = -P12;
        P[10] = 0.f; P[11] = 0.f;
    }
    __syncthreads();
}

// accumulate one broadcast pixel (ra..cc in scope) into 10 stats at APTR
#define ACC10(APTR, S)                                                      \
    {   float* A = (APTR);                                                  \
        A[0] += (S);                                                        \
        A[1] = fmaf((S), ra, A[1]);                                         \
        A[2] = fmaf((S), rb, A[2]);                                         \
        A[3] = fmaf((S), rc, A[3]);                                         \
        A[4] = fmaf((S), aa, A[4]);                                         \
        A[5] = fmaf((S), ab, A[5]);                                         \
        A[6] = fmaf((S), ac, A[6]);                                         \
        A[7] = fmaf((S), bb, A[7]);                                         \
        A[8] = fmaf((S), bc, A[8]);                                         \
        A[9] = fmaf((S), cc, A[9]);                                         }

// one quad source slot: DPP-broadcast pixel SRC_ of my quad, masked update
#define SRC_STEP(SRC_)                                                      \
    {   const float ra = dpp_f<(SRC_) * 0x55>(a);                           \
        const float rb = dpp_f<(SRC_) * 0x55>(b);                           \
        const float rc = dpp_f<(SRC_) * 0x55>(c);                           \
        const int   rm = dpp_i<(SRC_) * 0x55>(m);                           \
        const bool sel = (rm == q);                                         \
        const float aa = ra * ra, ab = ra * rb, ac = ra * rc;               \
        const float bb = rb * rb, bc = rb * rc, cc = rc * rc;               \
        if (MODE) {                                                         \
            const float rw0 = dpp_f<(SRC_) * 0x55>(ws0);                    \
            const float rw1 = dpp_f<(SRC_) * 0x55>(ws1);                    \
            const float rw2 = dpp_f<(SRC_) * 0x55>(ws2);                    \
            const float rw3 = dpp_f<(SRC_) * 0x55>(ws3);                    \
            { const float s = sel ? rw0 : 0.f; ACC10(&acc[0],  s) }         \
            { const float s = sel ? rw1 : 0.f; ACC10(&acc[10], s) }         \
            { const float s = sel ? rw2 : 0.f; ACC10(&acc[20], s) }         \
            { const float s = sel ? rw3 : 0.f; ACC10(&acc[30], s) }         \
        } else {                                                            \
            /* init: resp one-hot in g = n%4 = j */                         \
            const float s = sel ? 1.f : 0.f;                                \
            ACC10(&acc[j * 10], s)                                          \
        }                                                                   \
    }

// ---------- stats kernel: MODE 0 = init (g = n%4), MODE 1 = E+M step ----------
template<int MODE>
__global__ __launch_bounds__(NTHR, 4) void k_accum(const float* __restrict__ x,
                                                   const int* __restrict__ lab,
                                                   const float* __restrict__ sumsIn,
                                                   float* __restrict__ sumsOut,
                                                   int N) {
    __shared__ __align__(16) float spar[192];
    __shared__ float sums[160];
    __shared__ float wtab[16];
    __shared__ float sred[NTHR / 64][160];
    const int tid  = threadIdx.x;
    const int wave = tid >> 6, lane = tid & 63;
    const int q    = lane & 3;          // my role: mixture q
    if (MODE) compute_params(sumsIn, spar, sums, wtab, tid);

    float acc[40];                      // mixture q: 4 gaussians x 10 stats
    #pragma unroll
    for (int k = 0; k < 40; ++k) acc[k] = 0.f;

    const int groups = N >> 2;
    const int stride = gridDim.x * NTHR;
    const int gid    = blockIdx.x * NTHR + tid;
    const int trips  = (groups + stride - 1) / stride;
    const float4* x0p = (const float4*)x;
    const float4* x1p = (const float4*)(x + N);
    const float4* x2p = (const float4*)(x + 2 * N);
    const int4*   lp  = (const int4*)lab;

    for (int tr = 0; tr < trips; ++tr) {
        const int i  = tr * stride + gid;
        const bool valid = i < groups;
        const int ii = valid ? i : 0;
        float4 va = x0p[ii], vb = x1p[ii], vc = x2p[ii];
        int4   m4 = lp[ii];
        float pa[4] = {va.x, va.y, va.z, va.w};
        float pb[4] = {vb.x, vb.y, vb.z, vb.w};
        float pc[4] = {vc.x, vc.y, vc.z, vc.w};
        int   pm[4] = {m4.x, m4.y, m4.z, m4.w};
        if (!valid) { pm[0] = pm[1] = pm[2] = pm[3] = -1; }

        #pragma unroll
        for (int j = 0; j < 4; ++j) {      // pixel n = 4*i + j  ->  n%4 = j
            const float a = pa[j], b = pb[j], c = pc[j];
            const int   m = pm[j];
            float ws0 = 0.f, ws1 = 0.f, ws2 = 0.f, ws3 = 0.f;
            if (MODE) {
                // E-step for my own pixel (params of its mixture from LDS)
                const float* P0 = spar + (m & 3) * 48;
                float l[4];
                #pragma unroll
                for (int g = 0; g < 4; ++g) {
                    const float* P = P0 + g * 12;
                    float4 q0 = *(const float4*)(P);
                    float4 q1 = *(const float4*)(P + 4);
                    float2 q2 = *(const float2*)(P + 8);
                    l[g] = q0.w + q0.x * a + q0.y * b + q0.z * c
                         + q1.x * (a * a) + q1.y * (b * b) + q1.z * (c * c)
                         + q1.w * (a * b) + q2.x * (a * c) + q2.y * (b * c);
                }
                float mx = fmaxf(fmaxf(l[0], l[1]), fmaxf(l[2], l[3]));
                float e0 = __expf(l[0] - mx), e1 = __expf(l[1] - mx);
                float e2 = __expf(l[2] - mx), e3 = __expf(l[3] - mx);
                float rs = 1.0f / (e0 + e1 + e2 + e3);
                ws0 = e0 * rs; ws1 = e1 * rs; ws2 = e2 * rs; ws3 = e3 * rs;
            }
            SRC_STEP(0) SRC_STEP(1) SRC_STEP(2) SRC_STEP(3)
        }
    }

    // role classes align at {+4,+8} row_ror (DPP/VALU) + xor{16,32} (DS):
    // every lane ends with its class sum; lanes 0..3 carry mixture q.
    #pragma unroll
    for (int k = 0; k < 40; ++k) {
        float v = acc[k];
        v += dpp_f<0x124>(v);           // += lane+4  (row_ror:4, rows of 16)
        v += dpp_f<0x128>(v);           // += lane+8  (row_ror:8)
        v += __shfl_xor(v, 16, 64);
        v += __shfl_xor(v, 32, 64);
        acc[k] = v;
    }
    if (lane < 4) {                      // lane == mixture q; slot = q*40 + idx
        #pragma unroll
        for (int k = 0; k < 40; ++k) sred[wave][lane * 40 + k] = acc[k];
    }
    __syncthreads();
    if (tid < 160) {
        float s = sred[0][tid] + sred[1][tid] + sred[2][tid] + sred[3][tid];
        unsafeAtomicAdd(&sumsOut[tid * NBANK + (blockIdx.x & (NBANK - 1))], s);
    }
}

// ---------- final: all 16 gaussians -> logsumexp_g -> softmax_m ----------
__global__ __launch_bounds__(NTHR, 4) void k_final(const float* __restrict__ x,
                                                   const float* __restrict__ sumsIn,
                                                   float* __restrict__ out,
                                                   int N) {
    __shared__ __align__(16) float spar[192];
    __shared__ float sums[160];
    __shared__ float wtab[16];
    compute_params(sumsIn, spar, sums, wtab, threadIdx.x);
    const int lane = threadIdx.x & 63;
    const int q    = lane & 3;          // my role: mixture q
    float PR[40];                        // my mixture's 4 gaussians x 10
    #pragma unroll
    for (int g = 0; g < 4; ++g)
        #pragma unroll
        for (int k = 0; k < 10; ++k) PR[g * 10 + k] = spar[q * 48 + g * 12 + k];

    const int groups = N >> 2;
    const int stride = gridDim.x * NTHR;
    const int gid    = blockIdx.x * NTHR + threadIdx.x;
    const int trips  = (groups + stride - 1) / stride;
    const float4* x0p = (const float4*)x;
    const float4* x1p = (const float4*)(x + N);
    const float4* x2p = (const float4*)(x + 2 * N);

// per quad pixel P_: DPP-broadcast, my mixture's 4 logls -> logsumexp in M[P_]
#define FIN_P(P_)                                                           \
    {   const float ra = dpp_f<(P_) * 0x55>(a);                             \
        const float rb = dpp_f<(P_) * 0x55>(b);                             \
        const float rc = dpp_f<(P_) * 0x55>(c);                             \
        const float aa = ra * ra, ab = ra * rb, ac = ra * rc;               \
        const float bb = rb * rb, bc = rb * rc, cc = rc * rc;               \
        float l[4];                                                         \
        _Pragma("unroll")                                                   \
        for (int g = 0; g < 4; ++g) {                                       \
            const float* P = &PR[g * 10];                                   \
            l[g] = P[3] + P[0] * ra + P[1] * rb + P[2] * rc                 \
                 + P[4] * aa + P[5] * bb + P[6] * cc                        \
                 + P[7] * ab + P[8] * ac + P[9] * bc;                       \
        }                                                                   \
        float mx = fmaxf(fmaxf(l[0], l[1]), fmaxf(l[2], l[3]));             \
        M[P_] = mx + __logf(__expf(l[0] - mx) + __expf(l[1] - mx)          \
                          + __expf(l[2] - mx) + __expf(l[3] - mx));         \
    }

// quad transpose element (K_,QQ_): W[QQ_] = ml_{mixture QQ_}(my own pixel)
#define TRS(K_, QQ_)                                                        \
    {   const float v = dpp_f<(QQ_) * 0x55>(M[K_]);                         \
        if (q == (K_)) W[QQ_] = v;                                          }

    for (int tr = 0; tr < trips; ++tr) {
        const int i  = tr * stride + gid;
        const bool valid = i < groups;
        const int ii = valid ? i : 0;
        float4 va = x0p[ii], vb = x1p[ii], vc = x2p[ii];
        float pa[4] = {va.x, va.y, va.z, va.w};
        float pb[4] = {vb.x, vb.y, vb.z, vb.w};
        float pc[4] = {vc.x, vc.y, vc.z, vc.w};
        float po[4][4];                  // [j][mixture]

        #pragma unroll
        for (int j = 0; j < 4; ++j) {
            const float a = pa[j], b = pb[j], c = pc[j];
            float M[4];                  // ml_{my mixture}(quad pixel p)
            FIN_P(0) FIN_P(1) FIN_P(2) FIN_P(3)
            // 4x4 quad transpose via DPP: W[qq] = ml_{qq}(my pixel, slot q)
            float W[4] = {0.f, 0.f, 0.f, 0.f};
            TRS(0, 0) TRS(0, 1) TRS(0, 2) TRS(0, 3)
            TRS(1, 0) TRS(1, 1) TRS(1, 2) TRS(1, 3)
            TRS(2, 0) TRS(2, 1) TRS(2, 2) TRS(2, 3)
            TRS(3, 0) TRS(3, 1) TRS(3, 2) TRS(3, 3)
            float mmx = fmaxf(fmaxf(W[0], W[1]), fmaxf(W[2], W[3]));
            float e0 = __expf(W[0] - mmx), e1 = __expf(W[1] - mmx);
            float e2 = __expf(W[2] - mmx), e3 = __expf(W[3] - mmx);
            float rs = 1.0f / (e0 + e1 + e2 + e3);
            po[j][0] = e0 * rs; po[j][1] = e1 * rs;
            po[j][2] = e2 * rs; po[j][3] = e3 * rs;
        }
        if (valid) {
            #pragma unroll
            for (int m = 0; m < 4; ++m) {
                ((float4*)(out + (size_t)m * N))[i] =
                    make_float4(po[0][m], po[1][m], po[2][m], po[3][m]);
            }
        }
    }
}

extern "C" void kernel_launch(void* const* d_in, const int* in_sizes, int n_in,
                              void* d_out, int out_size, void* d_ws, size_t ws_size,
                              hipStream_t stream) {
    const float* x   = (const float*)d_in[0];   // [3, N] float32
    const int*   lab = (const int*)d_in[1];     // [N] int32 in [0,4)
    float* out = (float*)d_out;                 // [4, N] float32
    const int N = in_sizes[1];

    float* sums = (float*)d_ws;                 // [3 passes][160 slots][8 banks]
    hipMemsetAsync(sums, 0, 3 * 160 * NBANK * sizeof(float), stream);

    dim3 grid(NBLK), blk(NTHR);
    k_accum<0><<<grid, blk, 0, stream>>>(x, lab, sums, sums, N);
    k_accum<1><<<grid, blk, 0, stream>>>(x, lab, sums, sums + 1280, N);
    k_accum<1><<<grid, blk, 0, stream>>>(x, lab, sums + 1280, sums + 2560, N);
    k_final<<<grid, blk, 0, stream>>>(x, sums + 2560, out, N);
}

// Round 2
// 171.852 us; speedup vs baseline: 1.3679x; 1.3679x over previous
//
#include <hip/hip_runtime.h>
#include <math.h>

// GMM EM, M=4 mixtures x G=4 gaussians, C=3, EM_ITERS=3, EPS=1e-4.
// R8: fix the R7 spill. launch_bounds(256,4) capped VGPR at 64 (observed) ->
// acc[40]+pixel state spilled to scratch: 138MB writes/dispatch, kernels
// latency-bound at VALUBusy<12%. Revert to launch_bounds(256,2) (R6's
// VGPR=128, zero spill); hardware still co-residents 4 blocks/CU at 128
// VGPRs. Keep R7's wins-in-waiting: all quad-broadcast __shfl -> DPP
// quad_perm (VALU, no lgkmcnt), wave reduce xor4/xor8 -> DPP row_ror:4/8,
// grid 1024 blocks (trips==1 at N=2^20), atomic combine over 8 banks.
// Structure otherwise R6: lane role q = lane&3 owns mixture q, acc[40]/PR[40]
// in regs, masked FMA accumulate, banked global unsafeAtomicAdd, every block
// re-derives 16x12 params from sums.
// Pipeline: memset(15KB) -> accum0 -> accum1 -> accum2 -> final.

#define NTHR  256
#define NBLK  1024
#define NBANK 8
#define EPS_F 1e-4f
#define LOG2PI3 5.5136311992280366f   // 3*ln(2*pi)

// DPP helpers: ctrl 0x00-0xFF = quad_perm (src*0x55 = quad broadcast of src),
// 0x124 = row_ror:4, 0x128 = row_ror:8 (rows of 16 lanes).
template<int CTRL>
__device__ __forceinline__ float dpp_f(float v) {
    return __int_as_float(
        __builtin_amdgcn_mov_dpp(__float_as_int(v), CTRL, 0xF, 0xF, false));
}
template<int CTRL>
__device__ __forceinline__ int dpp_i(int v) {
    return __builtin_amdgcn_mov_dpp(v, CTRL, 0xF, 0xF, false);
}

// sums buffer per pass: [160 slots][NBANK banks] floats (slot = t*10+k)

// Derive E-step params from banked sums. spar layout per cluster t, stride 12:
// [0..2]=P*mu, [3]=c0, [4..6]=-0.5*Pii, [7..9]=-Pij(01,02,12), [10..11]=pad
static __device__ void compute_params(const float* __restrict__ sumsIn,
                                      float* spar, float* sums, float* wtab,
                                      int tid) {
    if (tid < 160) {
        float4 v0 = ((const float4*)sumsIn)[tid * 2];      // 8 banks
        float4 v1 = ((const float4*)sumsIn)[tid * 2 + 1];
        sums[tid] = ((v0.x + v0.y) + (v0.z + v0.w))
                  + ((v1.x + v1.y) + (v1.z + v1.w));
    }
    __syncthreads();
    if (tid < 16) wtab[tid] = sums[tid * 10] + EPS_F;
    __syncthreads();
    if (tid < 16) {
        const int tt = tid;
        const float* S = &sums[tt * 10];
        const float w  = wtab[tt];
        const float iw = 1.0f / w;
        float mu0 = S[1] * iw, mu1 = S[2] * iw, mu2 = S[3] * iw;
        float c00 = S[4] * iw - mu0 * mu0 + EPS_F;
        float c01 = S[5] * iw - mu0 * mu1;
        float c02 = S[6] * iw - mu0 * mu2;
        float c11 = S[7] * iw - mu1 * mu1 + EPS_F;
        float c12 = S[8] * iw - mu1 * mu2;
        float c22 = S[9] * iw - mu2 * mu2 + EPS_F;
        float d00 = c11 * c22 - c12 * c12;
        float d01 = c02 * c12 - c01 * c22;
        float d02 = c01 * c12 - c02 * c11;
        float det = c00 * d00 + c01 * d01 + c02 * d02;
        float idet = 1.0f / det;
        float P00 = d00 * idet, P01 = d01 * idet, P02 = d02 * idet;
        float P11 = (c00 * c22 - c02 * c02) * idet;
        float P12 = (c01 * c02 - c00 * c12) * idet;
        float P22 = (c00 * c11 - c01 * c01) * idet;
        float logdet = logf(det);
        const int mb = tt & 12;
        float wsum = wtab[mb] + wtab[mb + 1] + wtab[mb + 2] + wtab[mb + 3];
        float logpi = logf(w) - logf(wsum);
        float pm0 = P00 * mu0 + P01 * mu1 + P02 * mu2;
        float pm1 = P01 * mu0 + P11 * mu1 + P12 * mu2;
        float pm2 = P02 * mu0 + P12 * mu1 + P22 * mu2;
        float mPm = mu0 * pm0 + mu1 * pm1 + mu2 * pm2;
        float c0 = logpi - 0.5f * (mPm + logdet + LOG2PI3);
        float* P = spar + tt * 12;
        P[0] = pm0; P[1] = pm1; P[2] = pm2; P[3] = c0;
        P[4] = -0.5f * P00; P[5] = -0.5f * P11; P[6] = -0.5f * P22;
        P[7] = -P01; P[8] = -P02; P[9] = -P12;
        P[10] = 0.f; P[11] = 0.f;
    }
    __syncthreads();
}

// accumulate one broadcast pixel (ra..cc in scope) into 10 stats at APTR
#define ACC10(APTR, S)                                                      \
    {   float* A = (APTR);                                                  \
        A[0] += (S);                                                        \
        A[1] = fmaf((S), ra, A[1]);                                         \
        A[2] = fmaf((S), rb, A[2]);                                         \
        A[3] = fmaf((S), rc, A[3]);                                         \
        A[4] = fmaf((S), aa, A[4]);                                         \
        A[5] = fmaf((S), ab, A[5]);                                         \
        A[6] = fmaf((S), ac, A[6]);                                         \
        A[7] = fmaf((S), bb, A[7]);                                         \
        A[8] = fmaf((S), bc, A[8]);                                         \
        A[9] = fmaf((S), cc, A[9]);                                         }

// one quad source slot: DPP-broadcast pixel SRC_ of my quad, masked update
#define SRC_STEP(SRC_)                                                      \
    {   const float ra = dpp_f<(SRC_) * 0x55>(a);                           \
        const float rb = dpp_f<(SRC_) * 0x55>(b);                           \
        const float rc = dpp_f<(SRC_) * 0x55>(c);                           \
        const int   rm = dpp_i<(SRC_) * 0x55>(m);                           \
        const bool sel = (rm == q);                                         \
        const float aa = ra * ra, ab = ra * rb, ac = ra * rc;               \
        const float bb = rb * rb, bc = rb * rc, cc = rc * rc;               \
        if (MODE) {                                                         \
            const float rw0 = dpp_f<(SRC_) * 0x55>(ws0);                    \
            const float rw1 = dpp_f<(SRC_) * 0x55>(ws1);                    \
            const float rw2 = dpp_f<(SRC_) * 0x55>(ws2);                    \
            const float rw3 = dpp_f<(SRC_) * 0x55>(ws3);                    \
            { const float s = sel ? rw0 : 0.f; ACC10(&acc[0],  s) }         \
            { const float s = sel ? rw1 : 0.f; ACC10(&acc[10], s) }         \
            { const float s = sel ? rw2 : 0.f; ACC10(&acc[20], s) }         \
            { const float s = sel ? rw3 : 0.f; ACC10(&acc[30], s) }         \
        } else {                                                            \
            /* init: resp one-hot in g = n%4 = j */                         \
            const float s = sel ? 1.f : 0.f;                                \
            ACC10(&acc[j * 10], s)                                          \
        }                                                                   \
    }

// ---------- stats kernel: MODE 0 = init (g = n%4), MODE 1 = E+M step ----------
template<int MODE>
__global__ __launch_bounds__(NTHR, 2) void k_accum(const float* __restrict__ x,
                                                   const int* __restrict__ lab,
                                                   const float* __restrict__ sumsIn,
                                                   float* __restrict__ sumsOut,
                                                   int N) {
    __shared__ __align__(16) float spar[192];
    __shared__ float sums[160];
    __shared__ float wtab[16];
    __shared__ float sred[NTHR / 64][160];
    const int tid  = threadIdx.x;
    const int wave = tid >> 6, lane = tid & 63;
    const int q    = lane & 3;          // my role: mixture q
    if (MODE) compute_params(sumsIn, spar, sums, wtab, tid);

    float acc[40];                      // mixture q: 4 gaussians x 10 stats
    #pragma unroll
    for (int k = 0; k < 40; ++k) acc[k] = 0.f;

    const int groups = N >> 2;
    const int stride = gridDim.x * NTHR;
    const int gid    = blockIdx.x * NTHR + tid;
    const int trips  = (groups + stride - 1) / stride;
    const float4* x0p = (const float4*)x;
    const float4* x1p = (const float4*)(x + N);
    const float4* x2p = (const float4*)(x + 2 * N);
    const int4*   lp  = (const int4*)lab;

    for (int tr = 0; tr < trips; ++tr) {
        const int i  = tr * stride + gid;
        const bool valid = i < groups;
        const int ii = valid ? i : 0;
        float4 va = x0p[ii], vb = x1p[ii], vc = x2p[ii];
        int4   m4 = lp[ii];
        float pa[4] = {va.x, va.y, va.z, va.w};
        float pb[4] = {vb.x, vb.y, vb.z, vb.w};
        float pc[4] = {vc.x, vc.y, vc.z, vc.w};
        int   pm[4] = {m4.x, m4.y, m4.z, m4.w};
        if (!valid) { pm[0] = pm[1] = pm[2] = pm[3] = -1; }

        #pragma unroll
        for (int j = 0; j < 4; ++j) {      // pixel n = 4*i + j  ->  n%4 = j
            const float a = pa[j], b = pb[j], c = pc[j];
            const int   m = pm[j];
            float ws0 = 0.f, ws1 = 0.f, ws2 = 0.f, ws3 = 0.f;
            if (MODE) {
                // E-step for my own pixel (params of its mixture from LDS)
                const float* P0 = spar + (m & 3) * 48;
                float l[4];
                #pragma unroll
                for (int g = 0; g < 4; ++g) {
                    const float* P = P0 + g * 12;
                    float4 q0 = *(const float4*)(P);
                    float4 q1 = *(const float4*)(P + 4);
                    float2 q2 = *(const float2*)(P + 8);
                    l[g] = q0.w + q0.x * a + q0.y * b + q0.z * c
                         + q1.x * (a * a) + q1.y * (b * b) + q1.z * (c * c)
                         + q1.w * (a * b) + q2.x * (a * c) + q2.y * (b * c);
                }
                float mx = fmaxf(fmaxf(l[0], l[1]), fmaxf(l[2], l[3]));
                float e0 = __expf(l[0] - mx), e1 = __expf(l[1] - mx);
                float e2 = __expf(l[2] - mx), e3 = __expf(l[3] - mx);
                float rs = 1.0f / (e0 + e1 + e2 + e3);
                ws0 = e0 * rs; ws1 = e1 * rs; ws2 = e2 * rs; ws3 = e3 * rs;
            }
            SRC_STEP(0) SRC_STEP(1) SRC_STEP(2) SRC_STEP(3)
        }
    }

    // role classes align at {+4,+8} row_ror (DPP/VALU) + xor{16,32} (DS):
    // every lane ends with its class sum; lanes 0..3 carry mixture q.
    #pragma unroll
    for (int k = 0; k < 40; ++k) {
        float v = acc[k];
        v += dpp_f<0x124>(v);           // += lane+4  (row_ror:4, rows of 16)
        v += dpp_f<0x128>(v);           // += lane+8  (row_ror:8)
        v += __shfl_xor(v, 16, 64);
        v += __shfl_xor(v, 32, 64);
        acc[k] = v;
    }
    if (lane < 4) {                      // lane == mixture q; slot = q*40 + idx
        #pragma unroll
        for (int k = 0; k < 40; ++k) sred[wave][lane * 40 + k] = acc[k];
    }
    __syncthreads();
    if (tid < 160) {
        float s = sred[0][tid] + sred[1][tid] + sred[2][tid] + sred[3][tid];
        unsafeAtomicAdd(&sumsOut[tid * NBANK + (blockIdx.x & (NBANK - 1))], s);
    }
}

// ---------- final: all 16 gaussians -> logsumexp_g -> softmax_m ----------
__global__ __launch_bounds__(NTHR, 2) void k_final(const float* __restrict__ x,
                                                   const float* __restrict__ sumsIn,
                                                   float* __restrict__ out,
                                                   int N) {
    __shared__ __align__(16) float spar[192];
    __shared__ float sums[160];
    __shared__ float wtab[16];
    compute_params(sumsIn, spar, sums, wtab, threadIdx.x);
    const int lane = threadIdx.x & 63;
    const int q    = lane & 3;          // my role: mixture q
    float PR[40];                        // my mixture's 4 gaussians x 10
    #pragma unroll
    for (int g = 0; g < 4; ++g)
        #pragma unroll
        for (int k = 0; k < 10; ++k) PR[g * 10 + k] = spar[q * 48 + g * 12 + k];

    const int groups = N >> 2;
    const int stride = gridDim.x * NTHR;
    const int gid    = blockIdx.x * NTHR + threadIdx.x;
    const int trips  = (groups + stride - 1) / stride;
    const float4* x0p = (const float4*)x;
    const float4* x1p = (const float4*)(x + N);
    const float4* x2p = (const float4*)(x + 2 * N);

// per quad pixel P_: DPP-broadcast, my mixture's 4 logls -> logsumexp in M[P_]
#define FIN_P(P_)                                                           \
    {   const float ra = dpp_f<(P_) * 0x55>(a);                             \
        const float rb = dpp_f<(P_) * 0x55>(b);                             \
        const float rc = dpp_f<(P_) * 0x55>(c);                             \
        const float aa = ra * ra, ab = ra * rb, ac = ra * rc;               \
        const float bb = rb * rb, bc = rb * rc, cc = rc * rc;               \
        float l[4];                                                         \
        _Pragma("unroll")                                                   \
        for (int g = 0; g < 4; ++g) {                                       \
            const float* P = &PR[g * 10];                                   \
            l[g] = P[3] + P[0] * ra + P[1] * rb + P[2] * rc                 \
                 + P[4] * aa + P[5] * bb + P[6] * cc                        \
                 + P[7] * ab + P[8] * ac + P[9] * bc;                       \
        }                                                                   \
        float mx = fmaxf(fmaxf(l[0], l[1]), fmaxf(l[2], l[3]));             \
        M[P_] = mx + __logf(__expf(l[0] - mx) + __expf(l[1] - mx)          \
                          + __expf(l[2] - mx) + __expf(l[3] - mx));         \
    }

// quad transpose element (K_,QQ_): W[QQ_] = ml_{mixture QQ_}(my own pixel)
#define TRS(K_, QQ_)                                                        \
    {   const float v = dpp_f<(QQ_) * 0x55>(M[K_]);                         \
        if (q == (K_)) W[QQ_] = v;                                          }

    for (int tr = 0; tr < trips; ++tr) {
        const int i  = tr * stride + gid;
        const bool valid = i < groups;
        const int ii = valid ? i : 0;
        float4 va = x0p[ii], vb = x1p[ii], vc = x2p[ii];
        float pa[4] = {va.x, va.y, va.z, va.w};
        float pb[4] = {vb.x, vb.y, vb.z, vb.w};
        float pc[4] = {vc.x, vc.y, vc.z, vc.w};
        float po[4][4];                  // [j][mixture]

        #pragma unroll
        for (int j = 0; j < 4; ++j) {
            const float a = pa[j], b = pb[j], c = pc[j];
            float M[4];                  // ml_{my mixture}(quad pixel p)
            FIN_P(0) FIN_P(1) FIN_P(2) FIN_P(3)
            // 4x4 quad transpose via DPP: W[qq] = ml_{qq}(my pixel, slot q)
            float W[4] = {0.f, 0.f, 0.f, 0.f};
            TRS(0, 0) TRS(0, 1) TRS(0, 2) TRS(0, 3)
            TRS(1, 0) TRS(1, 1) TRS(1, 2) TRS(1, 3)
            TRS(2, 0) TRS(2, 1) TRS(2, 2) TRS(2, 3)
            TRS(3, 0) TRS(3, 1) TRS(3, 2) TRS(3, 3)
            float mmx = fmaxf(fmaxf(W[0], W[1]), fmaxf(W[2], W[3]));
            float e0 = __expf(W[0] - mmx), e1 = __expf(W[1] - mmx);
            float e2 = __expf(W[2] - mmx), e3 = __expf(W[3] - mmx);
            float rs = 1.0f / (e0 + e1 + e2 + e3);
            po[j][0] = e0 * rs; po[j][1] = e1 * rs;
            po[j][2] = e2 * rs; po[j][3] = e3 * rs;
        }
        if (valid) {
            #pragma unroll
            for (int m = 0; m < 4; ++m) {
                ((float4*)(out + (size_t)m * N))[i] =
                    make_float4(po[0][m], po[1][m], po[2][m], po[3][m]);
            }
        }
    }
}

extern "C" void kernel_launch(void* const* d_in, const int* in_sizes, int n_in,
                              void* d_out, int out_size, void* d_ws, size_t ws_size,
                              hipStream_t stream) {
    const float* x   = (const float*)d_in[0];   // [3, N] float32
    const int*   lab = (const int*)d_in[1];     // [N] int32 in [0,4)
    float* out = (float*)d_out;                 // [4, N] float32
    const int N = in_sizes[1];

    float* sums = (float*)d_ws;                 // [3 passes][160 slots][8 banks]
    hipMemsetAsync(sums, 0, 3 * 160 * NBANK * sizeof(float), stream);

    dim3 grid(NBLK), blk(NTHR);
    k_accum<0><<<grid, blk, 0, stream>>>(x, lab, sums, sums, N);
    k_accum<1><<<grid, blk, 0, stream>>>(x, lab, sums, sums + 1280, N);
    k_accum<1><<<grid, blk, 0, stream>>>(x, lab, sums + 1280, sums + 2560, N);
    k_final<<<grid, blk, 0, stream>>>(x, sums + 2560, out, N);
}

// Round 6
// 159.766 us; speedup vs baseline: 1.4714x; 1.0756x over previous
//
#include <hip/hip_runtime.h>
#include <math.h>

// GMM EM, M=4 mixtures x G=4 gaussians, C=3, EM_ITERS=3, EPS=1e-4.
// R12: fused EM via PERSISTENT KERNEL + software grid barrier (plain launch).
// R9-R11 failed bit-identically at absmax 0.265625 across three different
// coherence schemes -> the value is max|ref posterior| (ref ~0.25 +- noise,
// random labels make mixtures near-identical): out stayed memset-0, i.e.
// hipLaunchCooperativeKernel never ran (unchecked return; harness graph
// capture does not support cooperative launches). Fix: plain <<<>>> launch
// (graph-capturable, like passing R5-R8) + manual residency + manual barrier:
//   - NBLK=512, __launch_bounds__(256,2) -> VGPR<=128 (R6-proven no-spill)
//     -> 2 blocks/CU occupancy -> all 512 blocks resident at dispatch.
//   - barrier: monotonic arrival counter; arrive = returning
//     global_atomic_add sc0 sc1 (drained); lane0 spins on sc0|sc1 loads for
//     count >= k*NBLK; bounded polls failsafe (wrong-answer, never hang).
//   - sums: banked fadd atomics (RMW at device-coherent point, cross-XCD
//     proven by R5-R8) + sc0|sc1 direct reads (stale clean L2 lines from
//     the memset are never observed).
// Pixels are RE-READ each phase (L2/L3-resident, ~2us) instead of held in
// registers, keeping VGPR at the proven 128. Quad-role structure kept:
// lane role q=lane&3 owns mixture q, DPP quad_perm broadcasts, DPP row_ror
// + shfl_xor reduce, fresh banked sums buffer per phase.
// Pipeline: memset(15.4KB) -> k_fused { accum0 | bar | accum1 | bar |
//                                       accum2 | bar | final }.

#define NTHR  256
#define NBLK  512
#define NBANK 8
#define EPS_F 1e-4f
#define LOG2PI3 5.5136311992280366f   // 3*ln(2*pi)

typedef __attribute__((ext_vector_type(4))) float f32x4;

// ---- device-coherent primitives (explicit sc0/sc1 at ISA level) ----
// fadd executed at the device-coherent point.
__device__ __forceinline__ void atomic_add_dev(float* p, float v) {
    asm volatile("global_atomic_add_f32 %0, %1, off sc1"
                 :: "v"(p), "v"(v) : "memory");
}
// 8 contiguous floats (one slot's banks) read PAST L1/L2.
__device__ __forceinline__ float sum_banks_dev(const float* p) {
    f32x4 u, v;
    asm volatile(
        "global_load_dwordx4 %0, %2, off sc0 sc1\n\t"
        "global_load_dwordx4 %1, %2, off offset:16 sc0 sc1\n\t"
        "s_waitcnt vmcnt(0)"
        : "=&v"(u), "=&v"(v)
        : "v"(p)
        : "memory");
    return ((u.x + u.y) + (u.z + u.w)) + ((v.x + v.y) + (v.z + v.w));
}
// returning u32 atomic add (sc0 = return old), drained before return.
__device__ __forceinline__ unsigned atomic_inc_ret_dev(unsigned* p) {
    unsigned r, one = 1u;
    asm volatile("global_atomic_add %0, %1, %2, off sc0 sc1\n\t"
                 "s_waitcnt vmcnt(0)"
                 : "=v"(r) : "v"(p), "v"(one) : "memory");
    return r;
}
// coherent u32 load (bypass L1/L2).
__device__ __forceinline__ unsigned load_u32_dev(const unsigned* p) {
    unsigned r;
    asm volatile("global_load_dword %0, %1, off sc0 sc1\n\t"
                 "s_waitcnt vmcnt(0)"
                 : "=v"(r) : "v"(p) : "memory");
    return r;
}

// software grid barrier: monotonic counter, target = k*NBLK for k-th barrier.
// Bounded spin: on residency failure degrades to wrong answer, never a hang.
__device__ __forceinline__ void gbar(unsigned* cnt, unsigned target) {
    __syncthreads();                    // all block lanes done (atomics drained
                                        // by reduce_atomic's vmcnt(0))
    if (threadIdx.x == 0) {
        atomic_inc_ret_dev(cnt);        // arrival, complete at coherent point
        unsigned polls = 0;
        while (load_u32_dev(cnt) < target) {
            __builtin_amdgcn_s_sleep(2);
            if (++polls > (1u << 22)) break;    // failsafe
        }
    }
    __syncthreads();
}

// DPP helpers: ctrl 0x00-0xFF = quad_perm (src*0x55 = quad broadcast of src),
// 0x124 = row_ror:4, 0x128 = row_ror:8 (rows of 16 lanes).
template<int CTRL>
__device__ __forceinline__ float dpp_f(float v) {
    return __int_as_float(
        __builtin_amdgcn_mov_dpp(__float_as_int(v), CTRL, 0xF, 0xF, false));
}
template<int CTRL>
__device__ __forceinline__ int dpp_i(int v) {
    return __builtin_amdgcn_mov_dpp(v, CTRL, 0xF, 0xF, false);
}

// sums buffer per phase: [160 slots][NBANK banks] floats (slot = t*10+k)

// Derive E-step params from banked sums. spar layout per cluster t, stride 12:
// [0..2]=P*mu, [3]=c0, [4..6]=-0.5*Pii, [7..9]=-Pij(01,02,12), [10..11]=pad
static __device__ void compute_params(const float* __restrict__ sumsIn,
                                      float* spar, float* sums, float* wtab,
                                      int tid) {
    if (tid < 160) {
        sums[tid] = sum_banks_dev(sumsIn + tid * NBANK);
    }
    __syncthreads();
    if (tid < 16) wtab[tid] = sums[tid * 10] + EPS_F;
    __syncthreads();
    if (tid < 16) {
        const int tt = tid;
        const float* S = &sums[tt * 10];
        const float w  = wtab[tt];
        const float iw = 1.0f / w;
        float mu0 = S[1] * iw, mu1 = S[2] * iw, mu2 = S[3] * iw;
        float c00 = S[4] * iw - mu0 * mu0 + EPS_F;
        float c01 = S[5] * iw - mu0 * mu1;
        float c02 = S[6] * iw - mu0 * mu2;
        float c11 = S[7] * iw - mu1 * mu1 + EPS_F;
        float c12 = S[8] * iw - mu1 * mu2;
        float c22 = S[9] * iw - mu2 * mu2 + EPS_F;
        float d00 = c11 * c22 - c12 * c12;
        float d01 = c02 * c12 - c01 * c22;
        float d02 = c01 * c12 - c02 * c11;
        float det = c00 * d00 + c01 * d01 + c02 * d02;
        float idet = 1.0f / det;
        float P00 = d00 * idet, P01 = d01 * idet, P02 = d02 * idet;
        float P11 = (c00 * c22 - c02 * c02) * idet;
        float P12 = (c01 * c02 - c00 * c12) * idet;
        float P22 = (c00 * c11 - c01 * c01) * idet;
        float logdet = logf(det);
        const int mb = tt & 12;
        float wsum = wtab[mb] + wtab[mb + 1] + wtab[mb + 2] + wtab[mb + 3];
        float logpi = logf(w) - logf(wsum);
        float pm0 = P00 * mu0 + P01 * mu1 + P02 * mu2;
        float pm1 = P01 * mu0 + P11 * mu1 + P12 * mu2;
        float pm2 = P02 * mu0 + P12 * mu1 + P22 * mu2;
        float mPm = mu0 * pm0 + mu1 * pm1 + mu2 * pm2;
        float c0 = logpi - 0.5f * (mPm + logdet + LOG2PI3);
        float* P = spar + tt * 12;
        P[0] = pm0; P[1] = pm1; P[2] = pm2; P[3] = c0;
        P[4] = -0.5f * P00; P[5] = -0.5f * P11; P[6] = -0.5f * P22;
        P[7] = -P01; P[8] = -P02; P[9] = -P12;
        P[10] = 0.f; P[11] = 0.f;
    }
    __syncthreads();
}

// accumulate one broadcast pixel (ra..cc in scope) into 10 stats at APTR
#define ACC10(APTR, S)                                                      \
    {   float* A = (APTR);                                                  \
        A[0] += (S);                                                        \
        A[1] = fmaf((S), ra, A[1]);                                         \
        A[2] = fmaf((S), rb, A[2]);                                         \
        A[3] = fmaf((S), rc, A[3]);                                         \
        A[4] = fmaf((S), aa, A[4]);                                         \
        A[5] = fmaf((S), ab, A[5]);                                         \
        A[6] = fmaf((S), ac, A[6]);                                         \
        A[7] = fmaf((S), bb, A[7]);                                         \
        A[8] = fmaf((S), bc, A[8]);                                         \
        A[9] = fmaf((S), cc, A[9]);                                         }

// one quad source slot: DPP-broadcast pixel SRC_ of my quad, masked update
#define SRC_STEP(SRC_)                                                      \
    {   const float ra = dpp_f<(SRC_) * 0x55>(a);                           \
        const float rb = dpp_f<(SRC_) * 0x55>(b);                           \
        const float rc = dpp_f<(SRC_) * 0x55>(c);                           \
        const int   rm = dpp_i<(SRC_) * 0x55>(m);                           \
        const bool sel = (rm == q);                                         \
        const float aa = ra * ra, ab = ra * rb, ac = ra * rc;               \
        const float bb = rb * rb, bc = rb * rc, cc = rc * rc;               \
        if (MODE) {                                                         \
            const float rw0 = dpp_f<(SRC_) * 0x55>(ws0);                    \
            const float rw1 = dpp_f<(SRC_) * 0x55>(ws1);                    \
            const float rw2 = dpp_f<(SRC_) * 0x55>(ws2);                    \
            const float rw3 = dpp_f<(SRC_) * 0x55>(ws3);                    \
            { const float s = sel ? rw0 : 0.f; ACC10(&acc[0],  s) }         \
            { const float s = sel ? rw1 : 0.f; ACC10(&acc[10], s) }         \
            { const float s = sel ? rw2 : 0.f; ACC10(&acc[20], s) }         \
            { const float s = sel ? rw3 : 0.f; ACC10(&acc[30], s) }         \
        } else {                                                            \
            /* init: resp one-hot in g = n%4 = j */                         \
            const float s = sel ? 1.f : 0.f;                                \
            ACC10(&acc[j * 10], s)                                          \
        }                                                                   \
    }

// process one pixel (E-step if MODE, then quad-broadcast masked accumulate)
template<int MODE>
__device__ __forceinline__ void accum_pix(float a, float b, float c, int m,
                                          int j, const float* spar,
                                          float* acc, int q) {
    float ws0 = 0.f, ws1 = 0.f, ws2 = 0.f, ws3 = 0.f;
    if (MODE) {
        const float* P0 = spar + (m & 3) * 48;
        float l[4];
        #pragma unroll
        for (int g = 0; g < 4; ++g) {
            const float* P = P0 + g * 12;
            float4 q0 = *(const float4*)(P);
            float4 q1 = *(const float4*)(P + 4);
            float2 q2 = *(const float2*)(P + 8);
            l[g] = q0.w + q0.x * a + q0.y * b + q0.z * c
                 + q1.x * (a * a) + q1.y * (b * b) + q1.z * (c * c)
                 + q1.w * (a * b) + q2.x * (a * c) + q2.y * (b * c);
        }
        float mx = fmaxf(fmaxf(l[0], l[1]), fmaxf(l[2], l[3]));
        float e0 = __expf(l[0] - mx), e1 = __expf(l[1] - mx);
        float e2 = __expf(l[2] - mx), e3 = __expf(l[3] - mx);
        float rs = 1.0f / (e0 + e1 + e2 + e3);
        ws0 = e0 * rs; ws1 = e1 * rs; ws2 = e2 * rs; ws3 = e3 * rs;
    }
    SRC_STEP(0) SRC_STEP(1) SRC_STEP(2) SRC_STEP(3)
}

// one stats pass over this thread's pixels (grid-stride re-read of x/lab)
template<int MODE>
__device__ __forceinline__ void accum_phase(const float4* x0p,
                                            const float4* x1p,
                                            const float4* x2p,
                                            const int4* lp,
                                            int groups, int stride, int gid,
                                            const float* spar, float* acc,
                                            int q) {
    #pragma unroll
    for (int k = 0; k < 40; ++k) acc[k] = 0.f;
    for (int i = gid; i < groups; i += stride) {
        float4 va = x0p[i], vb = x1p[i], vc = x2p[i];
        int4   m4 = lp[i];
        accum_pix<MODE>(va.x, vb.x, vc.x, m4.x, 0, spar, acc, q);
        accum_pix<MODE>(va.y, vb.y, vc.y, m4.y, 1, spar, acc, q);
        accum_pix<MODE>(va.z, vb.z, vc.z, m4.z, 2, spar, acc, q);
        accum_pix<MODE>(va.w, vb.w, vc.w, m4.w, 3, spar, acc, q);
    }
}

// wave reduce (role classes align at +4/+8/xor16/xor32) -> LDS -> banked
// coherent atomic; drain (vmcnt(0)) so adds are globally visible before the
// block arrives at the grid barrier.
__device__ __forceinline__ void reduce_atomic(float* acc, float (*sred)[160],
                                              float* __restrict__ sumsOut,
                                              int tid, int wave, int lane) {
    #pragma unroll
    for (int k = 0; k < 40; ++k) {
        float v = acc[k];
        v += dpp_f<0x124>(v);           // += lane+4  (row_ror:4, rows of 16)
        v += dpp_f<0x128>(v);           // += lane+8  (row_ror:8)
        v += __shfl_xor(v, 16, 64);
        v += __shfl_xor(v, 32, 64);
        acc[k] = v;
    }
    if (lane < 4) {                      // lane == mixture q; slot = q*40 + k
        #pragma unroll
        for (int k = 0; k < 40; ++k) sred[wave][lane * 40 + k] = acc[k];
    }
    __syncthreads();
    if (tid < 160) {
        float s = sred[0][tid] + sred[1][tid] + sred[2][tid] + sred[3][tid];
        atomic_add_dev(&sumsOut[tid * NBANK + (blockIdx.x & (NBANK - 1))], s);
    }
    asm volatile("s_waitcnt vmcnt(0)" ::: "memory");
}

// posterior over mixtures for one pixel (quad-cooperative, DPP transpose)
__device__ __forceinline__ void final_quad(float a, float b, float c,
                                           const float* PR, int q,
                                           float* W) {
    float M[4];
    #define FIN_P(P_)                                                       \
    {   const float ra = dpp_f<(P_) * 0x55>(a);                             \
        const float rb = dpp_f<(P_) * 0x55>(b);                             \
        const float rc = dpp_f<(P_) * 0x55>(c);                             \
        const float aa = ra * ra, ab = ra * rb, ac = ra * rc;               \
        const float bb = rb * rb, bc = rb * rc, cc = rc * rc;               \
        float l[4];                                                         \
        _Pragma("unroll")                                                   \
        for (int g = 0; g < 4; ++g) {                                       \
            const float* P = &PR[g * 10];                                   \
            l[g] = P[3] + P[0] * ra + P[1] * rb + P[2] * rc                 \
                 + P[4] * aa + P[5] * bb + P[6] * cc                        \
                 + P[7] * ab + P[8] * ac + P[9] * bc;                       \
        }                                                                   \
        float mx = fmaxf(fmaxf(l[0], l[1]), fmaxf(l[2], l[3]));             \
        M[P_] = mx + __logf(__expf(l[0] - mx) + __expf(l[1] - mx)          \
                          + __expf(l[2] - mx) + __expf(l[3] - mx));         \
    }
    FIN_P(0) FIN_P(1) FIN_P(2) FIN_P(3)
    #undef FIN_P
    // 4x4 quad transpose via DPP: W[qq] = ml_{mixture qq}(my own pixel)
    W[0] = W[1] = W[2] = W[3] = 0.f;
    #define TRS(K_, QQ_)                                                    \
    {   const float v = dpp_f<(QQ_) * 0x55>(M[K_]);                         \
        if (q == (K_)) W[QQ_] = v;                                          }
    TRS(0, 0) TRS(0, 1) TRS(0, 2) TRS(0, 3)
    TRS(1, 0) TRS(1, 1) TRS(1, 2) TRS(1, 3)
    TRS(2, 0) TRS(2, 1) TRS(2, 2) TRS(2, 3)
    TRS(3, 0) TRS(3, 1) TRS(3, 2) TRS(3, 3)
    #undef TRS
    float mmx = fmaxf(fmaxf(W[0], W[1]), fmaxf(W[2], W[3]));
    float e0 = __expf(W[0] - mmx), e1 = __expf(W[1] - mmx);
    float e2 = __expf(W[2] - mmx), e3 = __expf(W[3] - mmx);
    float rs = 1.0f / (e0 + e1 + e2 + e3);
    W[0] = e0 * rs; W[1] = e1 * rs; W[2] = e2 * rs; W[3] = e3 * rs;
}

// ---------------- fused EM: 4 phases, 3 software grid barriers ----------------
__global__ __launch_bounds__(NTHR, 2) void k_fused(const float* __restrict__ x,
                                                   const int* __restrict__ lab,
                                                   float* __restrict__ sums,
                                                   unsigned* __restrict__ bar,
                                                   float* __restrict__ out,
                                                   int N) {
    __shared__ __align__(16) float spar[192];
    __shared__ float sumsh[160];
    __shared__ float wtab[16];
    __shared__ float sred[NTHR / 64][160];
    const int tid  = threadIdx.x;
    const int wave = tid >> 6, lane = tid & 63;
    const int q    = lane & 3;          // my role: mixture q
    const int groups = N >> 2;
    const int stride = gridDim.x * NTHR;
    const int gid    = blockIdx.x * NTHR + tid;
    const float4* x0p = (const float4*)x;
    const float4* x1p = (const float4*)(x + N);
    const float4* x2p = (const float4*)(x + 2 * N);
    const int4*   lp  = (const int4*)lab;

    float acc[40];                      // mixture q: 4 gaussians x 10 stats

    // ---- phase 0: init stats (resp one-hot at g = n%4) ----
    accum_phase<0>(x0p, x1p, x2p, lp, groups, stride, gid, spar, acc, q);
    reduce_atomic(acc, sred, sums, tid, wave, lane);
    gbar(bar, NBLK);

    // ---- phases 1,2: M-step(params) + E-step + stats ----
    #pragma unroll 1
    for (int p = 0; p < 2; ++p) {
        compute_params(sums + p * 1280, spar, sumsh, wtab, tid);
        accum_phase<1>(x0p, x1p, x2p, lp, groups, stride, gid, spar, acc, q);
        reduce_atomic(acc, sred, sums + (p + 1) * 1280, tid, wave, lane);
        gbar(bar, NBLK * (2 + p));
    }

    // ---- phase 3: final posterior ----
    compute_params(sums + 2560, spar, sumsh, wtab, tid);
    float PR[40];                        // my mixture's 4 gaussians x 10
    #pragma unroll
    for (int g = 0; g < 4; ++g)
        #pragma unroll
        for (int k = 0; k < 10; ++k) PR[g * 10 + k] = spar[q * 48 + g * 12 + k];

    for (int i = gid; i < groups; i += stride) {
        float4 va = x0p[i], vb = x1p[i], vc = x2p[i];
        float po[4][4];                  // [j][mixture]
        final_quad(va.x, vb.x, vc.x, PR, q, po[0]);
        final_quad(va.y, vb.y, vc.y, PR, q, po[1]);
        final_quad(va.z, vb.z, vc.z, PR, q, po[2]);
        final_quad(va.w, vb.w, vc.w, PR, q, po[3]);
        #pragma unroll
        for (int m = 0; m < 4; ++m) {
            ((float4*)(out + (size_t)m * N))[i] =
                make_float4(po[0][m], po[1][m], po[2][m], po[3][m]);
        }
    }
}

extern "C" void kernel_launch(void* const* d_in, const int* in_sizes, int n_in,
                              void* d_out, int out_size, void* d_ws, size_t ws_size,
                              hipStream_t stream) {
    const float* x   = (const float*)d_in[0];   // [3, N] float32
    const int*   lab = (const int*)d_in[1];     // [N] int32 in [0,4)
    float* out = (float*)d_out;                 // [4, N] float32
    const int N = in_sizes[1];

    float* sums   = (float*)d_ws;               // [3 phases][160 slots][8 banks]
    unsigned* bar = (unsigned*)(sums + 3 * 160 * NBANK);   // arrival counter
    hipMemsetAsync(d_ws, 0, (3 * 160 * NBANK + 4) * sizeof(float), stream);

    k_fused<<<dim3(NBLK), dim3(NTHR), 0, stream>>>(x, lab, sums, bar, out, N);
}

// Round 8
// 158.982 us; speedup vs baseline: 1.4786x; 1.0049x over previous
//
#include <hip/hip_runtime.h>
#include <math.h>

// GMM EM, M=4 mixtures x G=4 gaussians, C=3, EM_ITERS=3, EPS=1e-4.
// R14: fused persistent kernel (R12 base, NBLK=512 residency-proven) with a
// CACHED post-barrier params broadcast. Evidence so far:
//  - R13 (1024 blocks) stranded: VGPR 96 -> 128-granule -> 4 blocks/CU ->
//    capacity exactly 1024, zero slack; one lost slot -> failsafe timeout
//    (+2s pytest) -> partial sums (absmax 0.0156). Grid stays 512 (2/CU).
//  - R8 vs R6: same per-phase time at 2x occupancy -> phases are NOT
//    occupancy-limited; R12 fused phase = 33us with ~7us VALU issue ->
//    ~26us/phase overhead.
//  - Biggest quantified overhead: compute_params did 320 UNCACHED (sc0 sc1)
//    loads x 512 blocks = 164K serialized hits on 80 MALL lines per round.
// Experiment: sc1 atomics execute at the MALL without leaving per-XCD L2
// copies, and the dispatch-start acquire invalidated the memset's lines ->
// NORMAL CACHED loads of sums after the barrier are coherent: 1 miss/line
// per XCD, then L2 hits. Params rounds collapse to ~1us. Also: spin poll
// interval 128->512cy (4x less contention on the barrier line), failsafe
// 2^22->2^20 polls, bar counter on its own cache line (sums+4096 floats).
// Writes stay sc1 atomics (R12-proven); spin stays sc0|sc1.
// Pipeline: memset(16.4KB) -> k_fused { accum0 | bar | accum1 | bar |
//                                       accum2 | bar | final }.

#define NTHR  256
#define NBLK  512
#define NBANK 8
#define EPS_F 1e-4f
#define LOG2PI3 5.5136311992280366f   // 3*ln(2*pi)

// ---- device-coherent primitives (explicit sc0/sc1 at ISA level) ----
// fadd executed at the device-coherent point (no local-L2 allocation).
__device__ __forceinline__ void atomic_add_dev(float* p, float v) {
    asm volatile("global_atomic_add_f32 %0, %1, off sc1"
                 :: "v"(p), "v"(v) : "memory");
}
// returning u32 atomic add (sc0 = return old), drained before return.
__device__ __forceinline__ unsigned atomic_inc_ret_dev(unsigned* p) {
    unsigned r, one = 1u;
    asm volatile("global_atomic_add %0, %1, %2, off sc0 sc1\n\t"
                 "s_waitcnt vmcnt(0)"
                 : "=v"(r) : "v"(p), "v"(one) : "memory");
    return r;
}
// coherent u32 load (bypass L1/L2) for the barrier spin.
__device__ __forceinline__ unsigned load_u32_dev(const unsigned* p) {
    unsigned r;
    asm volatile("global_load_dword %0, %1, off sc0 sc1\n\t"
                 "s_waitcnt vmcnt(0)"
                 : "=v"(r) : "v"(p) : "memory");
    return r;
}

// software grid barrier: monotonic counter, target = k*NBLK for k-th barrier.
// Bounded spin: on residency failure degrades to wrong answer, never a hang.
__device__ __forceinline__ void gbar(unsigned* cnt, unsigned target) {
    __syncthreads();                    // all block lanes done (atomics drained
                                        // by reduce_atomic's vmcnt(0))
    if (threadIdx.x == 0) {
        atomic_inc_ret_dev(cnt);        // arrival, complete at coherent point
        unsigned polls = 0;
        while (load_u32_dev(cnt) < target) {
            __builtin_amdgcn_s_sleep(8);        // ~512cy poll interval
            if (++polls > (1u << 20)) break;    // failsafe (~0.6s)
        }
    }
    __syncthreads();
}

// DPP helpers: ctrl 0x00-0xFF = quad_perm (src*0x55 = quad broadcast of src),
// 0x124 = row_ror:4, 0x128 = row_ror:8 (rows of 16 lanes).
template<int CTRL>
__device__ __forceinline__ float dpp_f(float v) {
    return __int_as_float(
        __builtin_amdgcn_mov_dpp(__float_as_int(v), CTRL, 0xF, 0xF, false));
}
template<int CTRL>
__device__ __forceinline__ int dpp_i(int v) {
    return __builtin_amdgcn_mov_dpp(v, CTRL, 0xF, 0xF, false);
}

// sums buffer per phase: [160 slots][NBANK banks] floats (slot = t*10+k)

// Derive E-step params from banked sums. spar layout per cluster t, stride 12:
// [0..2]=P*mu, [3]=c0, [4..6]=-0.5*Pii, [7..9]=-Pij(01,02,12), [10..11]=pad
// sums reads: NORMAL CACHED float4 loads (the R14 experiment) — first touch
// per XCD misses to the MALL, the rest hit L2.
static __device__ void compute_params(const float* __restrict__ sumsIn,
                                      float* spar, float* sums, float* wtab,
                                      int tid) {
    if (tid < 160) {
        float4 v0 = ((const float4*)sumsIn)[tid * 2];      // 8 banks
        float4 v1 = ((const float4*)sumsIn)[tid * 2 + 1];
        sums[tid] = ((v0.x + v0.y) + (v0.z + v0.w))
                  + ((v1.x + v1.y) + (v1.z + v1.w));
    }
    __syncthreads();
    if (tid < 16) wtab[tid] = sums[tid * 10] + EPS_F;
    __syncthreads();
    if (tid < 16) {
        const int tt = tid;
        const float* S = &sums[tt * 10];
        const float w  = wtab[tt];
        const float iw = 1.0f / w;
        float mu0 = S[1] * iw, mu1 = S[2] * iw, mu2 = S[3] * iw;
        float c00 = S[4] * iw - mu0 * mu0 + EPS_F;
        float c01 = S[5] * iw - mu0 * mu1;
        float c02 = S[6] * iw - mu0 * mu2;
        float c11 = S[7] * iw - mu1 * mu1 + EPS_F;
        float c12 = S[8] * iw - mu1 * mu2;
        float c22 = S[9] * iw - mu2 * mu2 + EPS_F;
        float d00 = c11 * c22 - c12 * c12;
        float d01 = c02 * c12 - c01 * c22;
        float d02 = c01 * c12 - c02 * c11;
        float det = c00 * d00 + c01 * d01 + c02 * d02;
        float idet = 1.0f / det;
        float P00 = d00 * idet, P01 = d01 * idet, P02 = d02 * idet;
        float P11 = (c00 * c22 - c02 * c02) * idet;
        float P12 = (c01 * c02 - c00 * c12) * idet;
        float P22 = (c00 * c11 - c01 * c01) * idet;
        float logdet = logf(det);
        const int mb = tt & 12;
        float wsum = wtab[mb] + wtab[mb + 1] + wtab[mb + 2] + wtab[mb + 3];
        float logpi = logf(w) - logf(wsum);
        float pm0 = P00 * mu0 + P01 * mu1 + P02 * mu2;
        float pm1 = P01 * mu0 + P11 * mu1 + P12 * mu2;
        float pm2 = P02 * mu0 + P12 * mu1 + P22 * mu2;
        float mPm = mu0 * pm0 + mu1 * pm1 + mu2 * pm2;
        float c0 = logpi - 0.5f * (mPm + logdet + LOG2PI3);
        float* P = spar + tt * 12;
        P[0] = pm0; P[1] = pm1; P[2] = pm2; P[3] = c0;
        P[4] = -0.5f * P00; P[5] = -0.5f * P11; P[6] = -0.5f * P22;
        P[7] = -P01; P[8] = -P02; P[9] = -P12;
        P[10] = 0.f; P[11] = 0.f;
    }
    __syncthreads();
}

// accumulate one broadcast pixel (ra..cc in scope) into 10 stats at APTR
#define ACC10(APTR, S)                                                      \
    {   float* A = (APTR);                                                  \
        A[0] += (S);                                                        \
        A[1] = fmaf((S), ra, A[1]);                                         \
        A[2] = fmaf((S), rb, A[2]);                                         \
        A[3] = fmaf((S), rc, A[3]);                                         \
        A[4] = fmaf((S), aa, A[4]);                                         \
        A[5] = fmaf((S), ab, A[5]);                                         \
        A[6] = fmaf((S), ac, A[6]);                                         \
        A[7] = fmaf((S), bb, A[7]);                                         \
        A[8] = fmaf((S), bc, A[8]);                                         \
        A[9] = fmaf((S), cc, A[9]);                                         }

// one quad source slot: DPP-broadcast pixel SRC_ of my quad, masked update
#define SRC_STEP(SRC_)                                                      \
    {   const float ra = dpp_f<(SRC_) * 0x55>(a);                           \
        const float rb = dpp_f<(SRC_) * 0x55>(b);                           \
        const float rc = dpp_f<(SRC_) * 0x55>(c);                           \
        const int   rm = dpp_i<(SRC_) * 0x55>(m);                           \
        const bool sel = (rm == q);                                         \
        const float aa = ra * ra, ab = ra * rb, ac = ra * rc;               \
        const float bb = rb * rb, bc = rb * rc, cc = rc * rc;               \
        if (MODE) {                                                         \
            const float rw0 = dpp_f<(SRC_) * 0x55>(ws0);                    \
            const float rw1 = dpp_f<(SRC_) * 0x55>(ws1);                    \
            const float rw2 = dpp_f<(SRC_) * 0x55>(ws2);                    \
            const float rw3 = dpp_f<(SRC_) * 0x55>(ws3);                    \
            { const float s = sel ? rw0 : 0.f; ACC10(&acc[0],  s) }         \
            { const float s = sel ? rw1 : 0.f; ACC10(&acc[10], s) }         \
            { const float s = sel ? rw2 : 0.f; ACC10(&acc[20], s) }         \
            { const float s = sel ? rw3 : 0.f; ACC10(&acc[30], s) }         \
        } else {                                                            \
            /* init: resp one-hot in g = n%4 = j */                         \
            const float s = sel ? 1.f : 0.f;                                \
            ACC10(&acc[j * 10], s)                                          \
        }                                                                   \
    }

// process one pixel (E-step if MODE, then quad-broadcast masked accumulate)
template<int MODE>
__device__ __forceinline__ void accum_pix(float a, float b, float c, int m,
                                          int j, const float* spar,
                                          float* acc, int q) {
    float ws0 = 0.f, ws1 = 0.f, ws2 = 0.f, ws3 = 0.f;
    if (MODE) {
        const float* P0 = spar + (m & 3) * 48;
        float l[4];
        #pragma unroll
        for (int g = 0; g < 4; ++g) {
            const float* P = P0 + g * 12;
            float4 q0 = *(const float4*)(P);
            float4 q1 = *(const float4*)(P + 4);
            float2 q2 = *(const float2*)(P + 8);
            l[g] = q0.w + q0.x * a + q0.y * b + q0.z * c
                 + q1.x * (a * a) + q1.y * (b * b) + q1.z * (c * c)
                 + q1.w * (a * b) + q2.x * (a * c) + q2.y * (b * c);
        }
        float mx = fmaxf(fmaxf(l[0], l[1]), fmaxf(l[2], l[3]));
        float e0 = __expf(l[0] - mx), e1 = __expf(l[1] - mx);
        float e2 = __expf(l[2] - mx), e3 = __expf(l[3] - mx);
        float rs = 1.0f / (e0 + e1 + e2 + e3);
        ws0 = e0 * rs; ws1 = e1 * rs; ws2 = e2 * rs; ws3 = e3 * rs;
    }
    SRC_STEP(0) SRC_STEP(1) SRC_STEP(2) SRC_STEP(3)
}

// one stats pass over this thread's pixels (grid-stride re-read of x/lab)
template<int MODE>
__device__ __forceinline__ void accum_phase(const float4* x0p,
                                            const float4* x1p,
                                            const float4* x2p,
                                            const int4* lp,
                                            int groups, int stride, int gid,
                                            const float* spar, float* acc,
                                            int q) {
    #pragma unroll
    for (int k = 0; k < 40; ++k) acc[k] = 0.f;
    for (int i = gid; i < groups; i += stride) {
        float4 va = x0p[i], vb = x1p[i], vc = x2p[i];
        int4   m4 = lp[i];
        accum_pix<MODE>(va.x, vb.x, vc.x, m4.x, 0, spar, acc, q);
        accum_pix<MODE>(va.y, vb.y, vc.y, m4.y, 1, spar, acc, q);
        accum_pix<MODE>(va.z, vb.z, vc.z, m4.z, 2, spar, acc, q);
        accum_pix<MODE>(va.w, vb.w, vc.w, m4.w, 3, spar, acc, q);
    }
}

// wave reduce (role classes align at +4/+8/xor16/xor32) -> LDS -> banked
// coherent atomic; drain (vmcnt(0)) so adds are globally visible before the
// block arrives at the grid barrier.
__device__ __forceinline__ void reduce_atomic(float* acc, float (*sred)[160],
                                              float* __restrict__ sumsOut,
                                              int tid, int wave, int lane) {
    #pragma unroll
    for (int k = 0; k < 40; ++k) {
        float v = acc[k];
        v += dpp_f<0x124>(v);           // += lane+4  (row_ror:4, rows of 16)
        v += dpp_f<0x128>(v);           // += lane+8  (row_ror:8)
        v += __shfl_xor(v, 16, 64);
        v += __shfl_xor(v, 32, 64);
        acc[k] = v;
    }
    if (lane < 4) {                      // lane == mixture q; slot = q*40 + k
        #pragma unroll
        for (int k = 0; k < 40; ++k) sred[wave][lane * 40 + k] = acc[k];
    }
    __syncthreads();
    if (tid < 160) {
        float s = sred[0][tid] + sred[1][tid] + sred[2][tid] + sred[3][tid];
        atomic_add_dev(&sumsOut[tid * NBANK + (blockIdx.x & (NBANK - 1))], s);
    }
    asm volatile("s_waitcnt vmcnt(0)" ::: "memory");
}

// posterior over mixtures for one pixel (quad-cooperative, DPP transpose)
__device__ __forceinline__ void final_quad(float a, float b, float c,
                                           const float* PR, int q,
                                           float* W) {
    float M[4];
    #define FIN_P(P_)                                                       \
    {   const float ra = dpp_f<(P_) * 0x55>(a);                             \
        const float rb = dpp_f<(P_) * 0x55>(b);                             \
        const float rc = dpp_f<(P_) * 0x55>(c);                             \
        const float aa = ra * ra, ab = ra * rb, ac = ra * rc;               \
        const float bb = rb * rb, bc = rb * rc, cc = rc * rc;               \
        float l[4];                                                         \
        _Pragma("unroll")                                                   \
        for (int g = 0; g < 4; ++g) {                                       \
            const float* P = &PR[g * 10];                                   \
            l[g] = P[3] + P[0] * ra + P[1] * rb + P[2] * rc                 \
                 + P[4] * aa + P[5] * bb + P[6] * cc                        \
                 + P[7] * ab + P[8] * ac + P[9] * bc;                       \
        }                                                                   \
        float mx = fmaxf(fmaxf(l[0], l[1]), fmaxf(l[2], l[3]));             \
        M[P_] = mx + __logf(__expf(l[0] - mx) + __expf(l[1] - mx)          \
                          + __expf(l[2] - mx) + __expf(l[3] - mx));         \
    }
    FIN_P(0) FIN_P(1) FIN_P(2) FIN_P(3)
    #undef FIN_P
    // 4x4 quad transpose via DPP: W[qq] = ml_{mixture qq}(my own pixel)
    W[0] = W[1] = W[2] = W[3] = 0.f;
    #define TRS(K_, QQ_)                                                    \
    {   const float v = dpp_f<(QQ_) * 0x55>(M[K_]);                         \
        if (q == (K_)) W[QQ_] = v;                                          }
    TRS(0, 0) TRS(0, 1) TRS(0, 2) TRS(0, 3)
    TRS(1, 0) TRS(1, 1) TRS(1, 2) TRS(1, 3)
    TRS(2, 0) TRS(2, 1) TRS(2, 2) TRS(2, 3)
    TRS(3, 0) TRS(3, 1) TRS(3, 2) TRS(3, 3)
    #undef TRS
    float mmx = fmaxf(fmaxf(W[0], W[1]), fmaxf(W[2], W[3]));
    float e0 = __expf(W[0] - mmx), e1 = __expf(W[1] - mmx);
    float e2 = __expf(W[2] - mmx), e3 = __expf(W[3] - mmx);
    float rs = 1.0f / (e0 + e1 + e2 + e3);
    W[0] = e0 * rs; W[1] = e1 * rs; W[2] = e2 * rs; W[3] = e3 * rs;
}

// ---------------- fused EM: 4 phases, 3 software grid barriers ----------------
__global__ __launch_bounds__(NTHR, 2) void k_fused(const float* __restrict__ x,
                                                   const int* __restrict__ lab,
                                                   float* __restrict__ sums,
                                                   unsigned* __restrict__ bar,
                                                   float* __restrict__ out,
                                                   int N) {
    __shared__ __align__(16) float spar[192];
    __shared__ float sumsh[160];
    __shared__ float wtab[16];
    __shared__ float sred[NTHR / 64][160];
    const int tid  = threadIdx.x;
    const int wave = tid >> 6, lane = tid & 63;
    const int q    = lane & 3;          // my role: mixture q
    const int groups = N >> 2;
    const int stride = gridDim.x * NTHR;
    const int gid    = blockIdx.x * NTHR + tid;
    const float4* x0p = (const float4*)x;
    const float4* x1p = (const float4*)(x + N);
    const float4* x2p = (const float4*)(x + 2 * N);
    const int4*   lp  = (const int4*)lab;

    float acc[40];                      // mixture q: 4 gaussians x 10 stats

    // ---- phase 0: init stats (resp one-hot at g = n%4) ----
    accum_phase<0>(x0p, x1p, x2p, lp, groups, stride, gid, spar, acc, q);
    reduce_atomic(acc, sred, sums, tid, wave, lane);
    gbar(bar, NBLK);

    // ---- phases 1,2: M-step(params) + E-step + stats ----
    #pragma unroll 1
    for (int p = 0; p < 2; ++p) {
        compute_params(sums + p * 1280, spar, sumsh, wtab, tid);
        accum_phase<1>(x0p, x1p, x2p, lp, groups, stride, gid, spar, acc, q);
        reduce_atomic(acc, sred, sums + (p + 1) * 1280, tid, wave, lane);
        gbar(bar, NBLK * (2 + p));
    }

    // ---- phase 3: final posterior ----
    compute_params(sums + 2560, spar, sumsh, wtab, tid);
    float PR[40];                        // my mixture's 4 gaussians x 10
    #pragma unroll
    for (int g = 0; g < 4; ++g)
        #pragma unroll
        for (int k = 0; k < 10; ++k) PR[g * 10 + k] = spar[q * 48 + g * 12 + k];

    for (int i = gid; i < groups; i += stride) {
        float4 va = x0p[i], vb = x1p[i], vc = x2p[i];
        float po[4][4];                  // [j][mixture]
        final_quad(va.x, vb.x, vc.x, PR, q, po[0]);
        final_quad(va.y, vb.y, vc.y, PR, q, po[1]);
        final_quad(va.z, vb.z, vc.z, PR, q, po[2]);
        final_quad(va.w, vb.w, vc.w, PR, q, po[3]);
        #pragma unroll
        for (int m = 0; m < 4; ++m) {
            ((float4*)(out + (size_t)m * N))[i] =
                make_float4(po[0][m], po[1][m], po[2][m], po[3][m]);
        }
    }
}

extern "C" void kernel_launch(void* const* d_in, const int* in_sizes, int n_in,
                              void* d_out, int out_size, void* d_ws, size_t ws_size,
                              hipStream_t stream) {
    const float* x   = (const float*)d_in[0];   // [3, N] float32
    const int*   lab = (const int*)d_in[1];     // [N] int32 in [0,4)
    float* out = (float*)d_out;                 // [4, N] float32
    const int N = in_sizes[1];

    float* sums   = (float*)d_ws;               // [3 phases][160 slots][8 banks]
    unsigned* bar = (unsigned*)(sums + 4096);   // own cache line (16KB offset)
    hipMemsetAsync(d_ws, 0, 4100 * sizeof(float), stream);

    k_fused<<<dim3(NBLK), dim3(NTHR), 0, stream>>>(x, lab, sums, bar, out, N);
}